// Round 1
// baseline (207.093 us; speedup 1.0000x reference)
//
#include <hip/hip_runtime.h>
#include <hip/hip_bf16.h>

#define E 256
#define H 8
#define HD 32
#define T 768
#define B 4
#define BH 32
// segments: L=[0,300), A=[300,550), V=[550,768)

typedef __attribute__((ext_vector_type(8))) short bf16x8;
typedef __attribute__((ext_vector_type(4))) float f32x4;

__device__ __forceinline__ float b2f(__hip_bfloat16 x) { return __bfloat162float(x); }

__device__ __forceinline__ unsigned short f2bf_u(float x) {
    __hip_bfloat16 h = __float2bfloat16(x);
    return *(unsigned short*)&h;
}
__device__ __forceinline__ float bfu2f(unsigned short u) {
    return __uint_as_float(((unsigned int)u) << 16);
}

// split fp32[8] -> bf16 hi + lo fragments
__device__ __forceinline__ void f8_split(const float* v, bf16x8& h, bf16x8& l) {
    #pragma unroll
    for (int e = 0; e < 8; ++e) {
        unsigned short hu = f2bf_u(v[e]);
        h[e] = (short)hu;
        l[e] = (short)f2bf_u(v[e] - bfu2f(hu));
    }
}

#define MFMA3(ACC, AH, AL, BH_, BL_)                                         \
    ACC = __builtin_amdgcn_mfma_f32_16x16x32_bf16(AH, BH_, ACC, 0, 0, 0);    \
    ACC = __builtin_amdgcn_mfma_f32_16x16x32_bf16(AH, BL_, ACC, 0, 0, 0);    \
    ACC = __builtin_amdgcn_mfma_f32_16x16x32_bf16(AL, BH_, ACC, 0, 0, 0);

// dtype-agnostic scalar load: f32 ? float : bf16
__device__ __forceinline__ float ldu(const void* p, size_t i, int f32) {
    if (f32) return ((const float*)p)[i];
    return b2f(((const __hip_bfloat16*)p)[i]);
}

// G_i row loader (branch-summed s_*_w blocks)
__device__ __forceinline__ float gsum_load(int i, int r2, int r,
                                           const void* sl, const void* sa,
                                           const void* sv, int f32)
{
    size_t base = (size_t)r2 * 1024;
    switch (i) {
        case 0: return ldu(sl, base + r, f32) + ldu(sa, base + r, f32) + ldu(sv, base + r, f32);
        case 1: return ldu(sl, base + 256 + r, f32) + ldu(sa, base + 256 + r, f32);
        case 2: return ldu(sl, base + 512 + r, f32) + ldu(sv, base + 256 + r, f32);
        case 3: return ldu(sa, base + 512 + r, f32) + ldu(sv, base + 512 + r, f32);
        case 4: return ldu(sl, base + 768 + r, f32);
        case 5: return ldu(sa, base + 768 + r, f32);
        default: return ldu(sv, base + 768 + r, f32);
    }
}

// ---------------------------------------------------------------------------
// Kernel 0: input dtype detection (fp32 read as bf16 -> garbage exponents).
// ---------------------------------------------------------------------------
__global__ void detect_kernel(const unsigned short* __restrict__ q,
                              int* __restrict__ flag) {
    if (threadIdx.x == 0 && blockIdx.x == 0) {
        int f32 = 0;
        for (int i = 0; i < 256; ++i) {
            unsigned int bits = ((unsigned int)q[i]) << 16;
            float v = __uint_as_float(bits);
            if (!(v == v) || fabsf(v) > 1e4f) f32 = 1;
        }
        *flag = f32;
    }
}

// ---------------------------------------------------------------------------
// Kernel 0b (r17 + r18): one-shot conversion to bf16 hi/lo MFMA fragments.
//   XF[inp][rb 192][kb 8][lane][8]   (A: rows of q/k/v inputs)
//   WF[sec 3][cb 16][kb 8][lane][8]  (B: in_proj_w rows)
//   GF[i 7][rb 16][kb 8][lane][8]    (A: G_i rows, r18)
//   OWF[i 7][cb 16][kb 8][lane][8]   (B: out_w^T cols, r18)
// All live in the O-alias region (dead until attn; users run before attn).
// ---------------------------------------------------------------------------
__global__ __launch_bounds__(256) void conv_kernel(
    const void* query, const void* key, const void* value, const void* w,
    const void* sl, const void* sa, const void* sv, const void* outw,
    const int* __restrict__ flag,
    unsigned short* __restrict__ XFh, unsigned short* __restrict__ XFl,
    unsigned short* __restrict__ WFh, unsigned short* __restrict__ WFl,
    unsigned short* __restrict__ GFh, unsigned short* __restrict__ GFl,
    unsigned short* __restrict__ OWFh, unsigned short* __restrict__ OWFl)
{
    int f32 = *flag;
    int item = blockIdx.x * 256 + threadIdx.x;
    if (item < 294912) {                       // X: 3 inputs x 3072 rows x 32 kg
        int inp = item / 98304;
        int rem = item % 98304;
        int row = rem >> 5, kg = rem & 31;
        const void* X = (inp == 0) ? query : (inp == 1) ? key : value;
        float v[8];
        if (f32) {
            const float4* p = (const float4*)((const float*)X +
                               (size_t)row * 256 + kg * 8);
            *(float4*)&v[0] = p[0];
            *(float4*)&v[4] = p[1];
        } else {
            #pragma unroll
            for (int j = 0; j < 8; ++j)
                v[j] = ldu(X, (size_t)row * 256 + kg * 8 + j, 0);
        }
        bf16x8 h, l;
        f8_split(v, h, l);
        int rb = row >> 4, kb = kg >> 2;
        int lane = (row & 15) | ((kg & 3) << 4);
        size_t idx = (((size_t)(inp * 192 + rb) * 8 + kb) * 64 + lane) * 8;
        *(bf16x8*)&XFh[idx] = h;
        *(bf16x8*)&XFl[idx] = l;
    } else if (item < 319488) {                // W: 768 rows x 32 kg
        int rem = item - 294912;
        int gc = rem >> 5, kg = rem & 31;
        float v[8];
        if (f32) {
            const float4* p = (const float4*)((const float*)w +
                               (size_t)gc * 256 + kg * 8);
            *(float4*)&v[0] = p[0];
            *(float4*)&v[4] = p[1];
        } else {
            #pragma unroll
            for (int j = 0; j < 8; ++j)
                v[j] = ldu(w, (size_t)gc * 256 + kg * 8 + j, 0);
        }
        bf16x8 h, l;
        f8_split(v, h, l);
        int sec = gc >> 8, c = gc & 255;
        int cb = c >> 4, kb = kg >> 2;
        int lane = (c & 15) | ((kg & 3) << 4);
        size_t idx = (((size_t)(sec * 16 + cb) * 8 + kb) * 64 + lane) * 8;
        *(bf16x8*)&WFh[idx] = h;
        *(bf16x8*)&WFl[idx] = l;
    } else if (item < 376832) {                // G: 7 x 256 r2 x 32 kg
        int rem = item - 319488;
        int i = rem >> 13;
        int rest = rem & 8191;
        int r2 = rest >> 5, kg = rest & 31;
        float v[8];
        #pragma unroll
        for (int j = 0; j < 8; ++j)
            v[j] = gsum_load(i, r2, kg * 8 + j, sl, sa, sv, f32);
        bf16x8 h, l;
        f8_split(v, h, l);
        int rb = r2 >> 4, kb = kg >> 2;
        int lane = (r2 & 15) | ((kg & 3) << 4);
        size_t idx = (((size_t)(i * 16 + rb) * 8 + kb) * 64 + lane) * 8;
        *(bf16x8*)&GFh[idx] = h;
        *(bf16x8*)&GFl[idx] = l;
    } else if (item < 434176) {                // OW^T: 7 x 32 kg x 256 c
        int rem = item - 376832;
        int i = rem >> 13;
        int rest = rem & 8191;
        int kg = rest >> 8, c = rest & 255;
        float v[8];
        #pragma unroll
        for (int j = 0; j < 8; ++j)
            v[j] = ldu(outw, (size_t)i * 65536 + (kg * 8 + j) * 256 + c, f32);
        bf16x8 h, l;
        f8_split(v, h, l);
        int cb = c >> 4, kb = kg >> 2;
        int lane = (c & 15) | ((kg & 3) << 4);
        size_t idx = (((size_t)(i * 16 + cb) * 8 + kb) * 64 + lane) * 8;
        *(bf16x8*)&OWFh[idx] = h;
        *(bf16x8*)&OWFl[idx] = l;
    }
}

// ---------------------------------------------------------------------------
// Kernel 1 (proven round-17): QKV projection via MFMA.
// ---------------------------------------------------------------------------
__global__ __launch_bounds__(256) void qkv_mfma_kernel(
    const unsigned short* __restrict__ XFh, const unsigned short* __restrict__ XFl,
    const unsigned short* __restrict__ WFh, const unsigned short* __restrict__ WFl,
    const void* bias, const int* __restrict__ flag,
    float* __restrict__ qws,
    unsigned short* __restrict__ KGh, unsigned short* __restrict__ KGl,
    unsigned short* __restrict__ VGh, unsigned short* __restrict__ VGl)
{
    int f32 = *flag;
    int bx = blockIdx.x;          // 0..11: sec=bx>>2, colgroup=bx&3
    int rb = blockIdx.y;          // 0..191 rowblk
    int sec = bx >> 2, cg = bx & 3;
    int w = threadIdx.x >> 6, lane = threadIdx.x & 63;
    int m = lane & 15, quad = lane >> 4;
    int cb = cg * 4 + w;          // colblk 0..15 within section

    const unsigned short* Ah = XFh + (((size_t)(sec * 192 + rb) * 8) * 64 + lane) * 8;
    const unsigned short* Al = XFl + (((size_t)(sec * 192 + rb) * 8) * 64 + lane) * 8;
    const unsigned short* Bh = WFh + (((size_t)(sec * 16 + cb) * 8) * 64 + lane) * 8;
    const unsigned short* Bl = WFl + (((size_t)(sec * 16 + cb) * 8) * 64 + lane) * 8;

    f32x4 acc = {};
    #pragma unroll
    for (int kb = 0; kb < 8; ++kb) {
        size_t off = (size_t)kb * 512;
        bf16x8 ah = *(const bf16x8*)(Ah + off);
        bf16x8 al = *(const bf16x8*)(Al + off);
        bf16x8 bh = *(const bf16x8*)(Bh + off);
        bf16x8 bl = *(const bf16x8*)(Bl + off);
        MFMA3(acc, ah, al, bh, bl)
    }

    int c_local = cb * 16 + m;                 // col within section
    float bv = ldu(bias, sec * 256 + c_local, f32);
    int h = c_local >> 5, hd = c_local & 31;

    if (sec == 0) {
        #pragma unroll
        for (int rr = 0; rr < 4; ++rr) {
            int row = rb * 16 + quad * 4 + rr;
            int t = row >> 2, b = row & 3;
            float val = (acc[rr] + bv) * 0.17677669529663687f;
            qws[((size_t)((b * H + h) * T + t)) * HD + hd] = val;
        }
    } else if (sec == 1) {
        #pragma unroll
        for (int rr = 0; rr < 4; ++rr) {
            int row = rb * 16 + quad * 4 + rr;
            int s = row >> 2, b = row & 3;
            int bh_ = b * 8 + h, ch = s >> 6;
            float val = acc[rr] + bv;
            unsigned short hu = f2bf_u(val);
            unsigned short lu = f2bf_u(val - bfu2f(hu));
            size_t bi = (((size_t)(bh_ * 12 + ch) * 4 + ((s >> 4) & 3)) * 64
                         + ((s & 15) | ((hd >> 3) << 4))) * 8 + (hd & 7);
            KGh[bi] = hu;
            KGl[bi] = lu;
        }
    } else {
        #pragma unroll
        for (int rr = 0; rr < 4; ++rr) {
            int row = rb * 16 + quad * 4 + rr;
            int s = row >> 2, b = row & 3;
            int bh_ = b * 8 + h, ch = s >> 6;
            float val = acc[rr] + bv;
            unsigned short hu = f2bf_u(val);
            unsigned short lu = f2bf_u(val - bfu2f(hu));
            int sl = s & 63, ks = sl >> 5, j = sl & 7, q3 = (sl >> 3) & 3;
            int hdb = hd >> 4;
            size_t bi = ((((size_t)(bh_ * 12 + ch) * 2 + hdb) * 2 + ks) * 64
                         + ((hd & 15) | (q3 << 4))) * 8 + j;
            VGh[bi] = hu;
            VGl[bi] = lu;
        }
    }
}

// ---------------------------------------------------------------------------
// Kernel 1b (proven round-18): Mtmp_i = G_i @ out_w[i] via MFMA.
// ---------------------------------------------------------------------------
__global__ __launch_bounds__(256) void wcomb1_mfma_kernel(
    const unsigned short* __restrict__ GFh, const unsigned short* __restrict__ GFl,
    const unsigned short* __restrict__ OWFh, const unsigned short* __restrict__ OWFl,
    float* __restrict__ Mtmp)
{
    int cgrp = blockIdx.x;        // 0..3
    int rb   = blockIdx.y;        // 0..15 (r2 block)
    int i    = blockIdx.z;        // branch 0..6
    int w = threadIdx.x >> 6, lane = threadIdx.x & 63;
    int m = lane & 15, quad = lane >> 4;
    int cb = cgrp * 4 + w;        // c block 0..15

    const unsigned short* Ah = GFh + (((size_t)(i * 16 + rb) * 8) * 64 + lane) * 8;
    const unsigned short* Al = GFl + (((size_t)(i * 16 + rb) * 8) * 64 + lane) * 8;
    const unsigned short* Bh = OWFh + (((size_t)(i * 16 + cb) * 8) * 64 + lane) * 8;
    const unsigned short* Bl = OWFl + (((size_t)(i * 16 + cb) * 8) * 64 + lane) * 8;

    f32x4 acc = {};
    #pragma unroll
    for (int kb = 0; kb < 8; ++kb) {
        size_t off = (size_t)kb * 512;
        bf16x8 ah = *(const bf16x8*)(Ah + off);
        bf16x8 al = *(const bf16x8*)(Al + off);
        bf16x8 bh = *(const bf16x8*)(Bh + off);
        bf16x8 bl = *(const bf16x8*)(Bl + off);
        MFMA3(acc, ah, al, bh, bl)
    }
    #pragma unroll
    for (int rr = 0; rr < 4; ++rr) {
        int r2 = rb * 16 + quad * 4 + rr;
        Mtmp[(size_t)i * 65536 + r2 * 256 + cb * 16 + m] = acc[rr];
    }
}

// ---------------------------------------------------------------------------
// Kernel 2 (NEW round-19): s-split MFMA attention (flash-decoding style).
// Grid (24, 32, 2): z halves the s-chunk loop (ch 0..5 / 6..11) to double
// resident blocks/CU (3 -> 6; occupancy cap 37.5% -> 75%). Blocks emit
// fp32 per-segment partial accumulators + partial row-sums; the combine
// kernel below sums halves, normalizes, and does the 7-branch O store.
// ---------------------------------------------------------------------------
__global__ __launch_bounds__(256) void attn_mfma_kernel(
    const float* __restrict__ qws,
    const unsigned short* __restrict__ KGh, const unsigned short* __restrict__ KGl,
    const unsigned short* __restrict__ VGh, const unsigned short* __restrict__ VGl,
    float* __restrict__ PACC, float* __restrict__ PSUM)
{
    int tile = blockIdx.x;       // 0..23
    int bh   = blockIdx.y;       // 0..31
    int z    = blockIdx.z;       // 0..1  s-half
    int t0 = tile * 32;
    int tid = threadIdx.x;
    int w = tid >> 6, lane = tid & 63;
    int m = lane & 15, quad = lane >> 4;
    int tb = w & 1, hdb = w >> 1;

    __shared__ __align__(16) unsigned int EPK[2][2048];
    __shared__ float SP[4][16][3];

    bf16x8 aqh, aql;
    {
        const float* qr = qws + ((size_t)bh * T + t0 + tb * 16 + m) * HD + quad * 8;
        float qv[8];
        *(float4*)&qv[0] = *(const float4*)qr;
        *(float4*)&qv[4] = *(const float4*)(qr + 4);
        f8_split(qv, aqh, aql);
    }

    f32x4 acc0 = {}, acc1 = {}, acc2 = {};
    float ss0[4] = {}, ss1[4] = {}, ss2[4] = {};

    for (int ch = z * 6; ch < z * 6 + 6; ++ch) {
        int base = ch * 64;
        int buf = ch & 1;
        #pragma unroll
        for (int sbi = 0; sbi < 2; ++sbi) {
            int sb = (w >> 1) * 2 + sbi;
            size_t kfi = (((size_t)(bh * 12 + ch) * 4 + sb) * 64 + lane) * 8;
            bf16x8 bkh = *(const bf16x8*)(KGh + kfi);
            bf16x8 bkl = *(const bf16x8*)(KGl + kfi);
            f32x4 d = {};
            MFMA3(d, aqh, aql, bkh, bkl)
            int s64 = sb * 16 + m;
            int sglob = base + s64;
            int ksw = s64 >> 5, qp = (s64 >> 3) & 3, jp = m & 7;
            unsigned int* eb = &EPK[buf][(tb * 2 + ksw) * 512 + jp];
            #pragma unroll
            for (int r = 0; r < 4; ++r) {
                float e = __expf(d[r]);
                if (sglob < 300) ss0[r] += e;
                else if (sglob < 550) ss1[r] += e;
                else ss2[r] += e;
                unsigned short hu = f2bf_u(e);
                unsigned short lu = f2bf_u(e - bfu2f(hu));
                eb[((quad * 4 + r) + 16 * qp) * 8] =
                    (unsigned int)hu | ((unsigned int)lu << 16);
            }
        }
        __syncthreads();

        #pragma unroll
        for (int ks = 0; ks < 2; ++ks) {
            const unsigned int* ep = &EPK[buf][((tb * 2 + ks) * 64 + lane) * 8];
            uint4 p0 = *(const uint4*)ep;
            uint4 p1 = *(const uint4*)(ep + 4);
            bf16x8 aeh, ael;
            aeh[0] = (short)(p0.x & 0xffff); ael[0] = (short)(p0.x >> 16);
            aeh[1] = (short)(p0.y & 0xffff); ael[1] = (short)(p0.y >> 16);
            aeh[2] = (short)(p0.z & 0xffff); ael[2] = (short)(p0.z >> 16);
            aeh[3] = (short)(p0.w & 0xffff); ael[3] = (short)(p0.w >> 16);
            aeh[4] = (short)(p1.x & 0xffff); ael[4] = (short)(p1.x >> 16);
            aeh[5] = (short)(p1.y & 0xffff); ael[5] = (short)(p1.y >> 16);
            aeh[6] = (short)(p1.z & 0xffff); ael[6] = (short)(p1.z >> 16);
            aeh[7] = (short)(p1.w & 0xffff); ael[7] = (short)(p1.w >> 16);
            size_t vfi = ((((size_t)(bh * 12 + ch) * 2 + hdb) * 2 + ks) * 64 + lane) * 8;
            bf16x8 bvh = *(const bf16x8*)(VGh + vfi);
            bf16x8 bvl = *(const bf16x8*)(VGl + vfi);
            int s_lo = base + ks * 32;
            if (s_lo + 32 <= 300) { MFMA3(acc0, aeh, ael, bvh, bvl) }
            else if (s_lo >= 300 && s_lo + 32 <= 550) { MFMA3(acc1, aeh, ael, bvh, bvl) }
            else if (s_lo >= 550) { MFMA3(acc2, aeh, ael, bvh, bvl) }
            else {
                int bnd = (s_lo < 300) ? 300 : 550;
                bf16x8 eha = aeh, ela = ael, ehb = aeh, elb = ael;
                #pragma unroll
                for (int j = 0; j < 8; ++j) {
                    int s = s_lo + quad * 8 + j;
                    if (s < bnd) { ehb[j] = 0; elb[j] = 0; }
                    else         { eha[j] = 0; ela[j] = 0; }
                }
                if (s_lo < 300) { MFMA3(acc0, eha, ela, bvh, bvl)
                                  MFMA3(acc1, ehb, elb, bvh, bvl) }
                else            { MFMA3(acc1, eha, ela, bvh, bvl)
                                  MFMA3(acc2, ehb, elb, bvh, bvl) }
            }
        }
    }

    // partial row-sums (per hdb-half; combined across hdb here, across z later)
    #pragma unroll
    for (int sg = 0; sg < 3; ++sg)
        #pragma unroll
        for (int r = 0; r < 4; ++r) {
            float v = (sg == 0) ? ss0[r] : (sg == 1) ? ss1[r] : ss2[r];
            v += __shfl_down(v, 8, 16);
            v += __shfl_down(v, 4, 16);
            v += __shfl_down(v, 2, 16);
            v += __shfl_down(v, 1, 16);
            if (m == 0) SP[w][quad * 4 + r][sg] = v;
        }
    __syncthreads();

    // PACC[z][tile][bh][seg][t32][hd32], coalesced over m
    size_t pb = ((((size_t)z * 24 + tile) * 32 + bh) * 3) * 1024;
    #pragma unroll
    for (int r = 0; r < 4; ++r) {
        int idx = (tb * 16 + quad * 4 + r) * 32 + hdb * 16 + m;
        PACC[pb + idx]        = acc0[r];
        PACC[pb + 1024 + idx] = acc1[r];
        PACC[pb + 2048 + idx] = acc2[r];
    }
    // PSUM[z][tile][bh][seg][t32]
    if (tid < 96) {
        int sg = tid >> 5, t32 = tid & 31;
        int tbe = t32 >> 4, t16 = t32 & 15;
        PSUM[(((size_t)z * 24 + tile) * 32 + bh) * 96 + sg * 32 + t32] =
            SP[tbe][t16][sg] + SP[tbe + 2][t16][sg];
    }
}

// ---------------------------------------------------------------------------
// Kernel 2b (NEW round-19): combine z-halves, normalize, 7-branch O store
// (exact epilogue logic of the previous single-pass attention kernel).
// ---------------------------------------------------------------------------
__global__ __launch_bounds__(256) void attn_combine_kernel(
    const float* __restrict__ PACC, const float* __restrict__ PSUM,
    unsigned short* __restrict__ Ohi, unsigned short* __restrict__ Olo)
{
    int tile = blockIdx.x;       // 0..23
    int bh   = blockIdx.y;       // 0..31
    int tid = threadIdx.x;
    int tt = tid >> 3, q4 = tid & 7;

    size_t p0 = (((size_t)0 * 24 + tile) * 32 + bh) * 3072;
    size_t p1 = (((size_t)1 * 24 + tile) * 32 + bh) * 3072;
    float Pv[3][4], S[3];
    #pragma unroll
    for (int sg = 0; sg < 3; ++sg) {
        const float4 a = *(const float4*)&PACC[p0 + sg * 1024 + tt * 32 + q4 * 4];
        const float4 b = *(const float4*)&PACC[p1 + sg * 1024 + tt * 32 + q4 * 4];
        Pv[sg][0] = a.x + b.x; Pv[sg][1] = a.y + b.y;
        Pv[sg][2] = a.z + b.z; Pv[sg][3] = a.w + b.w;
        S[sg] = PSUM[((size_t)tile * 32 + bh) * 96 + sg * 32 + tt]
              + PSUM[((size_t)(24 + tile) * 32 + bh) * 96 + sg * 32 + tt];
    }

    int t_glob = tile * 32 + tt;
    int g = (t_glob < 300) ? 0 : (t_glob < 550 ? 1 : 2);
    int b_ = bh >> 3, h_ = bh & 7;
    int row = t_glob * B + b_;
    int lslot = (row & 15) + ((q4 >> 1) << 4);
    int j0 = (q4 & 1) * 4;
    size_t fbase = (((size_t)(row >> 4) * 56 + h_) * 64 + lslot) * 8 + j0;
    const int masks[7] = {7, 3, 5, 6, 1, 2, 4};
    #pragma unroll
    for (int i = 0; i < 7; ++i) {
        int mm = masks[i];
        float n0 = 0.f, n1 = 0.f, n2 = 0.f, n3 = 0.f, den = 0.f;
        if (mm & 1) { n0 += Pv[0][0]; n1 += Pv[0][1]; n2 += Pv[0][2]; n3 += Pv[0][3]; den += S[0]; }
        if (mm & 2) { n0 += Pv[1][0]; n1 += Pv[1][1]; n2 += Pv[1][2]; n3 += Pv[1][3]; den += S[1]; }
        if (mm & 4) { n0 += Pv[2][0]; n1 += Pv[2][1]; n2 += Pv[2][2]; n3 += Pv[2][3]; den += S[2]; }
        float r = 1.f / den;
        int live = (mm >> g) & 1;
        float o[4];
        o[0] = live ? n0 * r : 0.f;
        o[1] = live ? n1 * r : 0.f;
        o[2] = live ? n2 * r : 0.f;
        o[3] = live ? n3 * r : 0.f;
        ushort4 hi4, lo4;
        unsigned short* hp = (unsigned short*)&hi4;
        unsigned short* lp = (unsigned short*)&lo4;
        #pragma unroll
        for (int j = 0; j < 4; ++j) {
            unsigned short hu = f2bf_u(o[j]);
            hp[j] = hu;
            lp[j] = f2bf_u(o[j] - bfu2f(hu));
        }
        size_t addr = fbase + (size_t)i * (8 * 64 * 8);
        *(ushort4*)&Ohi[addr] = hi4;
        *(ushort4*)&Olo[addr] = lo4;
    }
}

// DT hi/lo fragment-major (proven round-15: 32x32 tiles, grid (8,8,7)).
__global__ __launch_bounds__(256) void wcomb2_gemm_kernel(
    const float* __restrict__ Mtmp, const void* finalw,
    const int* __restrict__ flag,
    unsigned short* __restrict__ DThi, unsigned short* __restrict__ DTlo)
{
    int f32 = *flag;
    int bx = blockIdx.x;   // e tile 0..7
    int by = blockIdx.y;   // c tile 0..7
    int i  = blockIdx.z;   // branch 0..6
    int tid = threadIdx.x;
    int tx = tid & 15, ty = tid >> 4;
    int colbase = bx * 32, rowbase = by * 32;
    __shared__ __align__(16) float AsT[32][34];
    __shared__ __align__(16) float Bs[32][34];
    float acc[2][2] = {};

    for (int kb = 0; kb < 8; ++kb) {
        __syncthreads();
        #pragma unroll
        for (int l = 0; l < 4; ++l) {
            int idx = l * 256 + tid;
            int c = idx & 31, kk = idx >> 5;
            AsT[kk][c] = Mtmp[(size_t)i * 65536 + (kb * 32 + kk) * 256 + rowbase + c];
            int k2 = idx & 31, n = idx >> 5;
            Bs[k2][n] = ldu(finalw, (size_t)(colbase + n) * 256 + kb * 32 + k2, f32);
        }
        __syncthreads();
        #pragma unroll 8
        for (int kk = 0; kk < 32; ++kk) {
            const float2 av = *(const float2*)&AsT[kk][ty * 2];
            const float2 bv = *(const float2*)&Bs[kk][tx * 2];
            acc[0][0] += av.x * bv.x; acc[0][1] += av.x * bv.y;
            acc[1][0] += av.y * bv.x; acc[1][1] += av.y * bv.y;
        }
    }
    #pragma unroll
    for (int u = 0; u < 2; ++u)
        #pragma unroll
        for (int v = 0; v < 2; ++v) {
            int c = rowbase + ty * 2 + u, e = colbase + tx * 2 + v;
            float a = acc[u][v];
            unsigned short hu = f2bf_u(a);
            size_t fidx = (((size_t)(e >> 4) * 56 + i * 8 + (c >> 5)) * 64
                           + (e & 15) + (((c >> 3) & 3) << 4)) * 8 + (c & 7);
            DThi[fidx] = hu;
            DTlo[fidx] = f2bf_u(a - bfu2f(hu));
        }
}

// ---------------------------------------------------------------------------
// Bias path (proven round-5). c0 aliases Mtmp (dead after wcomb2).
// ---------------------------------------------------------------------------
__global__ __launch_bounds__(256) void bias1_kernel(
    const void* sl, const void* sa, const void* sv, const void* outb,
    const void* slb, const void* sab, const void* svb,
    const int* __restrict__ flag, float* __restrict__ c0)
{
    int f32 = *flag;
    int r2 = blockIdx.x, m = threadIdx.x;
    __shared__ float red[256];
    float acc = 0.f;
    #pragma unroll
    for (int i = 0; i < 7; ++i)
        acc += ldu(outb, i * 256 + m, f32) * gsum_load(i, r2, m, sl, sa, sv, f32);
    red[m] = acc;
    __syncthreads();
    for (int s = 128; s > 0; s >>= 1) {
        if (m < s) red[m] += red[m + s];
        __syncthreads();
    }
    if (m == 0)
        c0[r2] = red[0] + ldu(slb, r2, f32) + ldu(sab, r2, f32) + ldu(svb, r2, f32);
}

__global__ __launch_bounds__(256) void bias2_kernel(
    const float* __restrict__ c0, const void* finalw, const void* finalb,
    const int* __restrict__ flag, float* __restrict__ d0)
{
    int f32 = *flag;
    int e = blockIdx.x, r = threadIdx.x;
    __shared__ float red[256];
    red[r] = c0[r] * ldu(finalw, (size_t)e * 256 + r, f32);
    __syncthreads();
    for (int s = 128; s > 0; s >>= 1) {
        if (r < s) red[r] += red[r + s];
        __syncthreads();
    }
    if (r == 0)
        d0[e] = red[0] + ldu(finalb, e, f32);
}

// ---------------------------------------------------------------------------
// Kernel 4 (proven round-13, MFMA + fragment-major): result = O@Dstack + d0.
// ---------------------------------------------------------------------------
__global__ __launch_bounds__(256) void final_gemm_mfma_kernel(
    const unsigned short* __restrict__ Ohi, const unsigned short* __restrict__ Olo,
    const unsigned short* __restrict__ DThi, const unsigned short* __restrict__ DTlo,
    const float* __restrict__ d0, const int* __restrict__ flag,
    void* __restrict__ outv)
{
    int f32 = *flag;
    int bx = blockIdx.x;
    int by = blockIdx.y;
    int w  = threadIdx.x >> 6;
    int lane = threadIdx.x & 63;
    int m = lane & 15, quad = lane >> 4;
    int R0 = by * 16, C0 = bx * 64 + w * 16;

    int t0 = R0 >> 2, t1 = (R0 + 15) >> 2;
    int g0 = (t0 < 300) ? 0 : (t0 < 550 ? 1 : 2);
    int g1 = (t1 < 300) ? 0 : (t1 < 550 ? 1 : 2);
    int activeset = (1 << g0) | (1 << g1);
    const int masks[7] = {7, 3, 5, 6, 1, 2, 4};

    const unsigned short* Abase_h = Ohi + (size_t)by * 56 * 512 + lane * 8;
    const unsigned short* Abase_l = Olo + (size_t)by * 56 * 512 + lane * 8;
    const unsigned short* Bbase_h = DThi + (size_t)(bx * 4 + w) * 56 * 512 + lane * 8;
    const unsigned short* Bbase_l = DTlo + (size_t)(bx * 4 + w) * 56 * 512 + lane * 8;

    f32x4 acc = {};
    for (int i = 0; i < 7; ++i) {
        if (!(masks[i] & activeset)) continue;
        #pragma unroll
        for (int kb = 0; kb < 8; ++kb) {
            size_t off = (size_t)(i * 8 + kb) * 512;
            bf16x8 ah = *(const bf16x8*)(Abase_h + off);
            bf16x8 al = *(const bf16x8*)(Abase_l + off);
            bf16x8 bh = *(const bf16x8*)(Bbase_h + off);
            bf16x8 bl = *(const bf16x8*)(Bbase_l + off);
            acc = __builtin_amdgcn_mfma_f32_16x16x32_bf16(ah, bh, acc, 0, 0, 0);
            acc = __builtin_amdgcn_mfma_f32_16x16x32_bf16(ah, bl, acc, 0, 0, 0);
            acc = __builtin_amdgcn_mfma_f32_16x16x32_bf16(al, bh, acc, 0, 0, 0);
        }
    }
    float dv = d0[C0 + m];
    #pragma unroll
    for (int r = 0; r < 4; ++r) {
        int row = R0 + quad * 4 + r;
        int col = C0 + m;
        float val = acc[r] + dv;
        if (f32) ((float*)outv)[(size_t)row * 256 + col] = val;
        else ((__hip_bfloat16*)outv)[(size_t)row * 256 + col] = __float2bfloat16(val);
    }
}

// ---------------------------------------------------------------------------
extern "C" void kernel_launch(void* const* d_in, const int* in_sizes, int n_in,
                              void* d_out, int out_size, void* d_ws, size_t ws_size,
                              hipStream_t stream) {
    const void* query     = d_in[0];
    const void* key       = d_in[1];
    const void* value     = d_in[2];
    const void* in_proj_w = d_in[3];
    const void* in_proj_b = d_in[4];
    const void* out_w     = d_in[5];
    const void* out_b     = d_in[6];
    const void* s_l_w     = d_in[7];
    const void* s_l_b     = d_in[8];
    const void* s_a_w     = d_in[9];
    const void* s_a_b     = d_in[10];
    const void* s_v_w     = d_in[11];
    const void* s_v_b     = d_in[12];
    const void* final_w   = d_in[13];
    const void* final_b   = d_in[14];

    float* ws     = (float*)d_ws;
    float* qws    = ws;                 //   786432 f (q fp32)
    unsigned short* KGh = (unsigned short*)(ws + 786432);
    unsigned short* KGl = KGh + 786432;
    unsigned short* VGh = (unsigned short*)(ws + 1572864);
    unsigned short* VGl = VGh + 786432;
    // O region [2359296, 7864320): Ohi/Olo for combine+final; aliased by the
    // conversion buffers XF/WF/GF/OWF (all consumed before combine writes O).
    unsigned short* Ohi = (unsigned short*)(ws + 2359296);   // 5505024 bf16
    unsigned short* Olo = (unsigned short*)(ws + 5111808);   // 5505024 bf16
    unsigned short* XFh = (unsigned short*)(ws + 2359296);   // 2359296 bf16
    unsigned short* XFl = XFh + 2359296;                     // 2359296 bf16
    unsigned short* WFh = XFl + 2359296;                     //  196608 bf16
    unsigned short* WFl = WFh + 196608;                      //  196608 bf16
    unsigned short* GFh = (unsigned short*)(ws + 4915200);   //  458752 bf16
    unsigned short* GFl = GFh + 458752;
    unsigned short* OWFh = GFl + 458752;                     //  458752 bf16
    unsigned short* OWFl = OWFh + 458752;                    // ends f 5832704
    float* Mtmp   = ws + 7864320;       //   458752 f
    unsigned short* DThi = (unsigned short*)(ws + 8323072);  // 458752 bf16
    unsigned short* DTlo = (unsigned short*)(ws + 8552448);  // 458752 bf16
    float* d0     = ws + 8781824;       //      256 f
    int*   flag   = (int*)(ws + 8782080);  // 1 int
    float* c0     = Mtmp;               // ALIAS: Mtmp dead after wcomb2
    // NEW round-19: attention split partials past the old high-water.
    // PACC [z2][tile24][bh32][seg3][32t][32hd] + PSUM [z2][tile24][bh32][seg3][32t]
    // New high-water f 13648384 (~54.6 MB). Old proven footprint (35.1 MB)
    // establishes ws_size >= 35.1 MB; pow2-default workspace => ws >= 64 MB.
    float* PACC   = ws + 8782336;       //  4718592 f
    float* PSUM   = ws + 13500928;      //   147456 f

    detect_kernel<<<1, 64, 0, stream>>>((const unsigned short*)query, flag);
    conv_kernel<<<1696, 256, 0, stream>>>(query, key, value, in_proj_w,
                                          s_l_w, s_a_w, s_v_w, out_w, flag,
                                          XFh, XFl, WFh, WFl,
                                          GFh, GFl, OWFh, OWFl);
    qkv_mfma_kernel<<<dim3(12, 192), 256, 0, stream>>>(XFh, XFl, WFh, WFl,
                                                       in_proj_b, flag, qws,
                                                       KGh, KGl, VGh, VGl);
    wcomb1_mfma_kernel<<<dim3(4, 16, 7), 256, 0, stream>>>(GFh, GFl, OWFh, OWFl,
                                                           Mtmp);
    attn_mfma_kernel<<<dim3(24, 32, 2), 256, 0, stream>>>(qws, KGh, KGl, VGh, VGl,
                                                          PACC, PSUM);
    attn_combine_kernel<<<dim3(24, 32), 256, 0, stream>>>(PACC, PSUM, Ohi, Olo);
    wcomb2_gemm_kernel<<<dim3(8, 8, 7), 256, 0, stream>>>(Mtmp, final_w, flag,
                                                          DThi, DTlo);
    bias1_kernel<<<256, 256, 0, stream>>>(s_l_w, s_a_w, s_v_w, out_b,
                                          s_l_b, s_a_b, s_v_b, flag, c0);
    bias2_kernel<<<256, 256, 0, stream>>>(c0, final_w, final_b, flag, d0);
    final_gemm_mfma_kernel<<<dim3(4, 192), 256, 0, stream>>>(Ohi, Olo, DThi, DTlo,
                                                             d0, flag, d_out);
}

// Round 2
// 194.777 us; speedup vs baseline: 1.0632x; 1.0632x over previous
//
#include <hip/hip_runtime.h>
#include <hip/hip_bf16.h>

#define E 256
#define H 8
#define HD 32
#define T 768
#define B 4
#define BH 32
// segments: L=[0,300), A=[300,550), V=[550,768)

typedef __attribute__((ext_vector_type(8))) short bf16x8;
typedef __attribute__((ext_vector_type(4))) float f32x4;

__device__ __forceinline__ float b2f(__hip_bfloat16 x) { return __bfloat162float(x); }

__device__ __forceinline__ unsigned short f2bf_u(float x) {
    __hip_bfloat16 h = __float2bfloat16(x);
    return *(unsigned short*)&h;
}
__device__ __forceinline__ float bfu2f(unsigned short u) {
    return __uint_as_float(((unsigned int)u) << 16);
}

// split fp32[8] -> bf16 hi + lo fragments
__device__ __forceinline__ void f8_split(const float* v, bf16x8& h, bf16x8& l) {
    #pragma unroll
    for (int e = 0; e < 8; ++e) {
        unsigned short hu = f2bf_u(v[e]);
        h[e] = (short)hu;
        l[e] = (short)f2bf_u(v[e] - bfu2f(hu));
    }
}

#define MFMA3(ACC, AH, AL, BH_, BL_)                                         \
    ACC = __builtin_amdgcn_mfma_f32_16x16x32_bf16(AH, BH_, ACC, 0, 0, 0);    \
    ACC = __builtin_amdgcn_mfma_f32_16x16x32_bf16(AH, BL_, ACC, 0, 0, 0);    \
    ACC = __builtin_amdgcn_mfma_f32_16x16x32_bf16(AL, BH_, ACC, 0, 0, 0);

// dtype-agnostic scalar load: f32 ? float : bf16
__device__ __forceinline__ float ldu(const void* p, size_t i, int f32) {
    if (f32) return ((const float*)p)[i];
    return b2f(((const __hip_bfloat16*)p)[i]);
}

// G_i row loader (branch-summed s_*_w blocks)
__device__ __forceinline__ float gsum_load(int i, int r2, int r,
                                           const void* sl, const void* sa,
                                           const void* sv, int f32)
{
    size_t base = (size_t)r2 * 1024;
    switch (i) {
        case 0: return ldu(sl, base + r, f32) + ldu(sa, base + r, f32) + ldu(sv, base + r, f32);
        case 1: return ldu(sl, base + 256 + r, f32) + ldu(sa, base + 256 + r, f32);
        case 2: return ldu(sl, base + 512 + r, f32) + ldu(sv, base + 256 + r, f32);
        case 3: return ldu(sa, base + 512 + r, f32) + ldu(sv, base + 512 + r, f32);
        case 4: return ldu(sl, base + 768 + r, f32);
        case 5: return ldu(sa, base + 768 + r, f32);
        default: return ldu(sv, base + 768 + r, f32);
    }
}

// ---------------------------------------------------------------------------
// Kernel 0: input dtype detection (fp32 read as bf16 -> garbage exponents).
// ---------------------------------------------------------------------------
__global__ void detect_kernel(const unsigned short* __restrict__ q,
                              int* __restrict__ flag) {
    if (threadIdx.x == 0 && blockIdx.x == 0) {
        int f32 = 0;
        for (int i = 0; i < 256; ++i) {
            unsigned int bits = ((unsigned int)q[i]) << 16;
            float v = __uint_as_float(bits);
            if (!(v == v) || fabsf(v) > 1e4f) f32 = 1;
        }
        *flag = f32;
    }
}

// ---------------------------------------------------------------------------
// Kernel 0b (r17 + r18): one-shot conversion to bf16 hi/lo MFMA fragments.
//   XF[inp][rb 192][kb 8][lane][8]   (A: rows of q/k/v inputs)
//   WF[sec 3][cb 16][kb 8][lane][8]  (B: in_proj_w rows)
//   GF[i 7][rb 16][kb 8][lane][8]    (A: G_i rows, r18)
//   OWF[i 7][cb 16][kb 8][lane][8]   (B: out_w^T cols, r18)
// All live in the O-alias region (dead until attn; users run before attn).
// ---------------------------------------------------------------------------
__global__ __launch_bounds__(256) void conv_kernel(
    const void* query, const void* key, const void* value, const void* w,
    const void* sl, const void* sa, const void* sv, const void* outw,
    const int* __restrict__ flag,
    unsigned short* __restrict__ XFh, unsigned short* __restrict__ XFl,
    unsigned short* __restrict__ WFh, unsigned short* __restrict__ WFl,
    unsigned short* __restrict__ GFh, unsigned short* __restrict__ GFl,
    unsigned short* __restrict__ OWFh, unsigned short* __restrict__ OWFl)
{
    int f32 = *flag;
    int item = blockIdx.x * 256 + threadIdx.x;
    if (item < 294912) {                       // X: 3 inputs x 3072 rows x 32 kg
        int inp = item / 98304;
        int rem = item % 98304;
        int row = rem >> 5, kg = rem & 31;
        const void* X = (inp == 0) ? query : (inp == 1) ? key : value;
        float v[8];
        if (f32) {
            const float4* p = (const float4*)((const float*)X +
                               (size_t)row * 256 + kg * 8);
            *(float4*)&v[0] = p[0];
            *(float4*)&v[4] = p[1];
        } else {
            #pragma unroll
            for (int j = 0; j < 8; ++j)
                v[j] = ldu(X, (size_t)row * 256 + kg * 8 + j, 0);
        }
        bf16x8 h, l;
        f8_split(v, h, l);
        int rb = row >> 4, kb = kg >> 2;
        int lane = (row & 15) | ((kg & 3) << 4);
        size_t idx = (((size_t)(inp * 192 + rb) * 8 + kb) * 64 + lane) * 8;
        *(bf16x8*)&XFh[idx] = h;
        *(bf16x8*)&XFl[idx] = l;
    } else if (item < 319488) {                // W: 768 rows x 32 kg
        int rem = item - 294912;
        int gc = rem >> 5, kg = rem & 31;
        float v[8];
        if (f32) {
            const float4* p = (const float4*)((const float*)w +
                               (size_t)gc * 256 + kg * 8);
            *(float4*)&v[0] = p[0];
            *(float4*)&v[4] = p[1];
        } else {
            #pragma unroll
            for (int j = 0; j < 8; ++j)
                v[j] = ldu(w, (size_t)gc * 256 + kg * 8 + j, 0);
        }
        bf16x8 h, l;
        f8_split(v, h, l);
        int sec = gc >> 8, c = gc & 255;
        int cb = c >> 4, kb = kg >> 2;
        int lane = (c & 15) | ((kg & 3) << 4);
        size_t idx = (((size_t)(sec * 16 + cb) * 8 + kb) * 64 + lane) * 8;
        *(bf16x8*)&WFh[idx] = h;
        *(bf16x8*)&WFl[idx] = l;
    } else if (item < 376832) {                // G: 7 x 256 r2 x 32 kg
        int rem = item - 319488;
        int i = rem >> 13;
        int rest = rem & 8191;
        int r2 = rest >> 5, kg = rest & 31;
        float v[8];
        #pragma unroll
        for (int j = 0; j < 8; ++j)
            v[j] = gsum_load(i, r2, kg * 8 + j, sl, sa, sv, f32);
        bf16x8 h, l;
        f8_split(v, h, l);
        int rb = r2 >> 4, kb = kg >> 2;
        int lane = (r2 & 15) | ((kg & 3) << 4);
        size_t idx = (((size_t)(i * 16 + rb) * 8 + kb) * 64 + lane) * 8;
        *(bf16x8*)&GFh[idx] = h;
        *(bf16x8*)&GFl[idx] = l;
    } else if (item < 434176) {                // OW^T: 7 x 32 kg x 256 c
        int rem = item - 376832;
        int i = rem >> 13;
        int rest = rem & 8191;
        int kg = rest >> 8, c = rest & 255;
        float v[8];
        #pragma unroll
        for (int j = 0; j < 8; ++j)
            v[j] = ldu(outw, (size_t)i * 65536 + (kg * 8 + j) * 256 + c, f32);
        bf16x8 h, l;
        f8_split(v, h, l);
        int cb = c >> 4, kb = kg >> 2;
        int lane = (c & 15) | ((kg & 3) << 4);
        size_t idx = (((size_t)(i * 16 + cb) * 8 + kb) * 64 + lane) * 8;
        *(bf16x8*)&OWFh[idx] = h;
        *(bf16x8*)&OWFl[idx] = l;
    }
}

// ---------------------------------------------------------------------------
// Kernel 1 (proven round-17): QKV projection via MFMA.
// ---------------------------------------------------------------------------
__global__ __launch_bounds__(256) void qkv_mfma_kernel(
    const unsigned short* __restrict__ XFh, const unsigned short* __restrict__ XFl,
    const unsigned short* __restrict__ WFh, const unsigned short* __restrict__ WFl,
    const void* bias, const int* __restrict__ flag,
    float* __restrict__ qws,
    unsigned short* __restrict__ KGh, unsigned short* __restrict__ KGl,
    unsigned short* __restrict__ VGh, unsigned short* __restrict__ VGl)
{
    int f32 = *flag;
    int bx = blockIdx.x;          // 0..11: sec=bx>>2, colgroup=bx&3
    int rb = blockIdx.y;          // 0..191 rowblk
    int sec = bx >> 2, cg = bx & 3;
    int w = threadIdx.x >> 6, lane = threadIdx.x & 63;
    int m = lane & 15, quad = lane >> 4;
    int cb = cg * 4 + w;          // colblk 0..15 within section

    const unsigned short* Ah = XFh + (((size_t)(sec * 192 + rb) * 8) * 64 + lane) * 8;
    const unsigned short* Al = XFl + (((size_t)(sec * 192 + rb) * 8) * 64 + lane) * 8;
    const unsigned short* Bh = WFh + (((size_t)(sec * 16 + cb) * 8) * 64 + lane) * 8;
    const unsigned short* Bl = WFl + (((size_t)(sec * 16 + cb) * 8) * 64 + lane) * 8;

    f32x4 acc = {};
    #pragma unroll
    for (int kb = 0; kb < 8; ++kb) {
        size_t off = (size_t)kb * 512;
        bf16x8 ah = *(const bf16x8*)(Ah + off);
        bf16x8 al = *(const bf16x8*)(Al + off);
        bf16x8 bh = *(const bf16x8*)(Bh + off);
        bf16x8 bl = *(const bf16x8*)(Bl + off);
        MFMA3(acc, ah, al, bh, bl)
    }

    int c_local = cb * 16 + m;                 // col within section
    float bv = ldu(bias, sec * 256 + c_local, f32);
    int h = c_local >> 5, hd = c_local & 31;

    if (sec == 0) {
        #pragma unroll
        for (int rr = 0; rr < 4; ++rr) {
            int row = rb * 16 + quad * 4 + rr;
            int t = row >> 2, b = row & 3;
            float val = (acc[rr] + bv) * 0.17677669529663687f;
            qws[((size_t)((b * H + h) * T + t)) * HD + hd] = val;
        }
    } else if (sec == 1) {
        #pragma unroll
        for (int rr = 0; rr < 4; ++rr) {
            int row = rb * 16 + quad * 4 + rr;
            int s = row >> 2, b = row & 3;
            int bh_ = b * 8 + h, ch = s >> 6;
            float val = acc[rr] + bv;
            unsigned short hu = f2bf_u(val);
            unsigned short lu = f2bf_u(val - bfu2f(hu));
            size_t bi = (((size_t)(bh_ * 12 + ch) * 4 + ((s >> 4) & 3)) * 64
                         + ((s & 15) | ((hd >> 3) << 4))) * 8 + (hd & 7);
            KGh[bi] = hu;
            KGl[bi] = lu;
        }
    } else {
        #pragma unroll
        for (int rr = 0; rr < 4; ++rr) {
            int row = rb * 16 + quad * 4 + rr;
            int s = row >> 2, b = row & 3;
            int bh_ = b * 8 + h, ch = s >> 6;
            float val = acc[rr] + bv;
            unsigned short hu = f2bf_u(val);
            unsigned short lu = f2bf_u(val - bfu2f(hu));
            int sl = s & 63, ks = sl >> 5, j = sl & 7, q3 = (sl >> 3) & 3;
            int hdb = hd >> 4;
            size_t bi = ((((size_t)(bh_ * 12 + ch) * 2 + hdb) * 2 + ks) * 64
                         + ((hd & 15) | (q3 << 4))) * 8 + j;
            VGh[bi] = hu;
            VGl[bi] = lu;
        }
    }
}

// ---------------------------------------------------------------------------
// Kernel 1b (proven round-18): Mtmp_i = G_i @ out_w[i] via MFMA.
// ---------------------------------------------------------------------------
__global__ __launch_bounds__(256) void wcomb1_mfma_kernel(
    const unsigned short* __restrict__ GFh, const unsigned short* __restrict__ GFl,
    const unsigned short* __restrict__ OWFh, const unsigned short* __restrict__ OWFl,
    float* __restrict__ Mtmp)
{
    int cgrp = blockIdx.x;        // 0..3
    int rb   = blockIdx.y;        // 0..15 (r2 block)
    int i    = blockIdx.z;        // branch 0..6
    int w = threadIdx.x >> 6, lane = threadIdx.x & 63;
    int m = lane & 15, quad = lane >> 4;
    int cb = cgrp * 4 + w;        // c block 0..15

    const unsigned short* Ah = GFh + (((size_t)(i * 16 + rb) * 8) * 64 + lane) * 8;
    const unsigned short* Al = GFl + (((size_t)(i * 16 + rb) * 8) * 64 + lane) * 8;
    const unsigned short* Bh = OWFh + (((size_t)(i * 16 + cb) * 8) * 64 + lane) * 8;
    const unsigned short* Bl = OWFl + (((size_t)(i * 16 + cb) * 8) * 64 + lane) * 8;

    f32x4 acc = {};
    #pragma unroll
    for (int kb = 0; kb < 8; ++kb) {
        size_t off = (size_t)kb * 512;
        bf16x8 ah = *(const bf16x8*)(Ah + off);
        bf16x8 al = *(const bf16x8*)(Al + off);
        bf16x8 bh = *(const bf16x8*)(Bh + off);
        bf16x8 bl = *(const bf16x8*)(Bl + off);
        MFMA3(acc, ah, al, bh, bl)
    }
    #pragma unroll
    for (int rr = 0; rr < 4; ++rr) {
        int r2 = rb * 16 + quad * 4 + rr;
        Mtmp[(size_t)i * 65536 + r2 * 256 + cb * 16 + m] = acc[rr];
    }
}

// ---------------------------------------------------------------------------
// Kernel 2 (round-20): single-pass MFMA attention (reverted z-split) with
//   (a) register prefetch of K/V fragments for chunk ch+1 issued at the top
//       of iteration ch (loads drain at the barrier AFTER the QK+exp+pack
//       phase instead of stalling the first dependent MFMA), and
//   (b) XOR-swizzled EPK addressing  w ^= ((w>>5)&7)<<2  (involution applied
//       identically on write and read; write conflicts 8-way -> ~2-way,
//       read b128 16-deep -> 8-clk floor).
// ---------------------------------------------------------------------------
__global__ __launch_bounds__(256, 3) void attn_mfma_kernel(
    const float* __restrict__ qws,
    const unsigned short* __restrict__ KGh, const unsigned short* __restrict__ KGl,
    const unsigned short* __restrict__ VGh, const unsigned short* __restrict__ VGl,
    unsigned short* __restrict__ Ohi, unsigned short* __restrict__ Olo)
{
    int tile = blockIdx.x;       // 0..23
    int bh   = blockIdx.y;       // 0..31
    int t0 = tile * 32;
    int tid = threadIdx.x;
    int w = tid >> 6, lane = tid & 63;
    int m = lane & 15, quad = lane >> 4;
    int tb = w & 1, hdb = w >> 1;

    __shared__ __align__(16) unsigned int EPK[2][2048];
    __shared__ float SP[4][16][3];
    float* PL = (float*)&EPK[0][0];

    bf16x8 aqh, aql;
    {
        const float* qr = qws + ((size_t)bh * T + t0 + tb * 16 + m) * HD + quad * 8;
        float qv[8];
        *(float4*)&qv[0] = *(const float4*)qr;
        *(float4*)&qv[4] = *(const float4*)(qr + 4);
        f8_split(qv, aqh, aql);
    }

    f32x4 acc0 = {}, acc1 = {}, acc2 = {};
    float ss0[4] = {}, ss1[4] = {}, ss2[4] = {};

    int sb0 = (w >> 1) * 2;      // this wave's K sub-block base (0 or 2)

    // --- prefetch chunk 0 fragments into registers ---
    bf16x8 ckh0, ckl0, ckh1, ckl1, cvh0, cvl0, cvh1, cvl1;
    {
        size_t k0 = (((size_t)(bh * 12 + 0) * 4 + sb0) * 64 + lane) * 8;
        ckh0 = *(const bf16x8*)(KGh + k0);       ckl0 = *(const bf16x8*)(KGl + k0);
        ckh1 = *(const bf16x8*)(KGh + k0 + 512); ckl1 = *(const bf16x8*)(KGl + k0 + 512);
        size_t v0 = ((((size_t)(bh * 12 + 0) * 2 + hdb) * 2) * 64 + lane) * 8;
        cvh0 = *(const bf16x8*)(VGh + v0);       cvl0 = *(const bf16x8*)(VGl + v0);
        cvh1 = *(const bf16x8*)(VGh + v0 + 512); cvl1 = *(const bf16x8*)(VGl + v0 + 512);
    }

    #pragma unroll 2
    for (int ch = 0; ch < 12; ++ch) {
        int base = ch * 64;
        int buf = ch & 1;

        // --- issue next-chunk loads EARLY (hidden under QK phase) ---
        bf16x8 nkh0, nkl0, nkh1, nkl1, nvh0, nvl0, nvh1, nvl1;
        if (ch < 11) {
            size_t kn = (((size_t)(bh * 12 + ch + 1) * 4 + sb0) * 64 + lane) * 8;
            nkh0 = *(const bf16x8*)(KGh + kn);       nkl0 = *(const bf16x8*)(KGl + kn);
            nkh1 = *(const bf16x8*)(KGh + kn + 512); nkl1 = *(const bf16x8*)(KGl + kn + 512);
            size_t vn = ((((size_t)(bh * 12 + ch + 1) * 2 + hdb) * 2) * 64 + lane) * 8;
            nvh0 = *(const bf16x8*)(VGh + vn);       nvl0 = *(const bf16x8*)(VGl + vn);
            nvh1 = *(const bf16x8*)(VGh + vn + 512); nvl1 = *(const bf16x8*)(VGl + vn + 512);
        }

        // --- QK phase (uses prefetched current-chunk K) ---
        #pragma unroll
        for (int sbi = 0; sbi < 2; ++sbi) {
            bf16x8 bkh = sbi ? ckh1 : ckh0;
            bf16x8 bkl = sbi ? ckl1 : ckl0;
            f32x4 d = {};
            MFMA3(d, aqh, aql, bkh, bkl)
            int sb = sb0 + sbi;
            int s64 = sb * 16 + m;
            int sglob = base + s64;
            int ksw = s64 >> 5, qp = (s64 >> 3) & 3, jp = m & 7;
            int wbase = (tb * 2 + ksw) * 512 + jp;
            #pragma unroll
            for (int r = 0; r < 4; ++r) {
                float e = __expf(d[r]);
                if (sglob < 300) ss0[r] += e;
                else if (sglob < 550) ss1[r] += e;
                else ss2[r] += e;
                unsigned short hu = f2bf_u(e);
                unsigned short lu = f2bf_u(e - bfu2f(hu));
                int wi = wbase + ((quad * 4 + r) + 16 * qp) * 8;
                wi ^= ((wi >> 5) & 7) << 2;       // bank swizzle
                EPK[buf][wi] = (unsigned int)hu | ((unsigned int)lu << 16);
            }
        }
        __syncthreads();

        // --- PV phase (uses prefetched current-chunk V) ---
        #pragma unroll
        for (int ks = 0; ks < 2; ++ks) {
            int ri = (tb * 2 + ks) * 512 + lane * 8;
            int rs = ri ^ (((ri >> 5) & 7) << 2); // bank swizzle (same involution)
            const unsigned int* e0 = &EPK[buf][rs];
            const unsigned int* e1 = &EPK[buf][rs ^ 4];
            uint4 p0 = *(const uint4*)e0;
            uint4 p1 = *(const uint4*)e1;
            bf16x8 aeh, ael;
            aeh[0] = (short)(p0.x & 0xffff); ael[0] = (short)(p0.x >> 16);
            aeh[1] = (short)(p0.y & 0xffff); ael[1] = (short)(p0.y >> 16);
            aeh[2] = (short)(p0.z & 0xffff); ael[2] = (short)(p0.z >> 16);
            aeh[3] = (short)(p0.w & 0xffff); ael[3] = (short)(p0.w >> 16);
            aeh[4] = (short)(p1.x & 0xffff); ael[4] = (short)(p1.x >> 16);
            aeh[5] = (short)(p1.y & 0xffff); ael[5] = (short)(p1.y >> 16);
            aeh[6] = (short)(p1.z & 0xffff); ael[6] = (short)(p1.z >> 16);
            aeh[7] = (short)(p1.w & 0xffff); ael[7] = (short)(p1.w >> 16);
            bf16x8 bvh = ks ? cvh1 : cvh0;
            bf16x8 bvl = ks ? cvl1 : cvl0;
            int s_lo = base + ks * 32;
            if (s_lo + 32 <= 300) { MFMA3(acc0, aeh, ael, bvh, bvl) }
            else if (s_lo >= 300 && s_lo + 32 <= 550) { MFMA3(acc1, aeh, ael, bvh, bvl) }
            else if (s_lo >= 550) { MFMA3(acc2, aeh, ael, bvh, bvl) }
            else {
                int bnd = (s_lo < 300) ? 300 : 550;
                bf16x8 eha = aeh, ela = ael, ehb = aeh, elb = ael;
                #pragma unroll
                for (int j = 0; j < 8; ++j) {
                    int s = s_lo + quad * 8 + j;
                    if (s < bnd) { ehb[j] = 0; elb[j] = 0; }
                    else         { eha[j] = 0; ela[j] = 0; }
                }
                if (s_lo < 300) { MFMA3(acc0, eha, ela, bvh, bvl)
                                  MFMA3(acc1, ehb, elb, bvh, bvl) }
                else            { MFMA3(acc1, eha, ela, bvh, bvl)
                                  MFMA3(acc2, ehb, elb, bvh, bvl) }
            }
        }

        // --- rotate prefetched registers ---
        if (ch < 11) {
            ckh0 = nkh0; ckl0 = nkl0; ckh1 = nkh1; ckl1 = nkl1;
            cvh0 = nvh0; cvl0 = nvl0; cvh1 = nvh1; cvl1 = nvl1;
        }
    }

    #pragma unroll
    for (int sg = 0; sg < 3; ++sg)
        #pragma unroll
        for (int r = 0; r < 4; ++r) {
            float v = (sg == 0) ? ss0[r] : (sg == 1) ? ss1[r] : ss2[r];
            v += __shfl_down(v, 8, 16);
            v += __shfl_down(v, 4, 16);
            v += __shfl_down(v, 2, 16);
            v += __shfl_down(v, 1, 16);
            if (m == 0) SP[w][quad * 4 + r][sg] = v;
        }
    __syncthreads();

    #pragma unroll
    for (int r = 0; r < 4; ++r) {
        int t32 = tb * 16 + quad * 4 + r;
        int hd = hdb * 16 + m;
        PL[0 * 1152 + t32 * 36 + hd] = acc0[r];
        PL[1 * 1152 + t32 * 36 + hd] = acc1[r];
        PL[2 * 1152 + t32 * 36 + hd] = acc2[r];
    }
    __syncthreads();

    int tt = tid >> 3, q4 = tid & 7;
    float Pv[3][4];
    #pragma unroll
    for (int sg = 0; sg < 3; ++sg) {
        const float4 p = *(const float4*)&PL[sg * 1152 + tt * 36 + q4 * 4];
        Pv[sg][0] = p.x; Pv[sg][1] = p.y; Pv[sg][2] = p.z; Pv[sg][3] = p.w;
    }
    int tbe = tt >> 4, t16 = tt & 15;
    float S0 = SP[tbe][t16][0] + SP[tbe + 2][t16][0];
    float S1 = SP[tbe][t16][1] + SP[tbe + 2][t16][1];
    float S2 = SP[tbe][t16][2] + SP[tbe + 2][t16][2];

    int t_glob = t0 + tt;
    int g = (t_glob < 300) ? 0 : (t_glob < 550 ? 1 : 2);
    int b_ = bh >> 3, h_ = bh & 7;
    int row = t_glob * B + b_;
    int lslot = (row & 15) + ((q4 >> 1) << 4);
    int j0 = (q4 & 1) * 4;
    size_t fbase = (((size_t)(row >> 4) * 56 + h_) * 64 + lslot) * 8 + j0;
    const int masks[7] = {7, 3, 5, 6, 1, 2, 4};
    #pragma unroll
    for (int i = 0; i < 7; ++i) {
        int mm = masks[i];
        float n0 = 0.f, n1 = 0.f, n2 = 0.f, n3 = 0.f, den = 0.f;
        if (mm & 1) { n0 += Pv[0][0]; n1 += Pv[0][1]; n2 += Pv[0][2]; n3 += Pv[0][3]; den += S0; }
        if (mm & 2) { n0 += Pv[1][0]; n1 += Pv[1][1]; n2 += Pv[1][2]; n3 += Pv[1][3]; den += S1; }
        if (mm & 4) { n0 += Pv[2][0]; n1 += Pv[2][1]; n2 += Pv[2][2]; n3 += Pv[2][3]; den += S2; }
        float r = 1.f / den;
        int live = (mm >> g) & 1;
        float o[4];
        o[0] = live ? n0 * r : 0.f;
        o[1] = live ? n1 * r : 0.f;
        o[2] = live ? n2 * r : 0.f;
        o[3] = live ? n3 * r : 0.f;
        ushort4 hi4, lo4;
        unsigned short* hp = (unsigned short*)&hi4;
        unsigned short* lp = (unsigned short*)&lo4;
        #pragma unroll
        for (int j = 0; j < 4; ++j) {
            unsigned short hu = f2bf_u(o[j]);
            hp[j] = hu;
            lp[j] = f2bf_u(o[j] - bfu2f(hu));
        }
        size_t addr = fbase + (size_t)i * (8 * 64 * 8);
        *(ushort4*)&Ohi[addr] = hi4;
        *(ushort4*)&Olo[addr] = lo4;
    }
}

// DT hi/lo fragment-major (proven round-15: 32x32 tiles, grid (8,8,7)).
__global__ __launch_bounds__(256) void wcomb2_gemm_kernel(
    const float* __restrict__ Mtmp, const void* finalw,
    const int* __restrict__ flag,
    unsigned short* __restrict__ DThi, unsigned short* __restrict__ DTlo)
{
    int f32 = *flag;
    int bx = blockIdx.x;   // e tile 0..7
    int by = blockIdx.y;   // c tile 0..7
    int i  = blockIdx.z;   // branch 0..6
    int tid = threadIdx.x;
    int tx = tid & 15, ty = tid >> 4;
    int colbase = bx * 32, rowbase = by * 32;
    __shared__ __align__(16) float AsT[32][34];
    __shared__ __align__(16) float Bs[32][34];
    float acc[2][2] = {};

    for (int kb = 0; kb < 8; ++kb) {
        __syncthreads();
        #pragma unroll
        for (int l = 0; l < 4; ++l) {
            int idx = l * 256 + tid;
            int c = idx & 31, kk = idx >> 5;
            AsT[kk][c] = Mtmp[(size_t)i * 65536 + (kb * 32 + kk) * 256 + rowbase + c];
            int k2 = idx & 31, n = idx >> 5;
            Bs[k2][n] = ldu(finalw, (size_t)(colbase + n) * 256 + kb * 32 + k2, f32);
        }
        __syncthreads();
        #pragma unroll 8
        for (int kk = 0; kk < 32; ++kk) {
            const float2 av = *(const float2*)&AsT[kk][ty * 2];
            const float2 bv = *(const float2*)&Bs[kk][tx * 2];
            acc[0][0] += av.x * bv.x; acc[0][1] += av.x * bv.y;
            acc[1][0] += av.y * bv.x; acc[1][1] += av.y * bv.y;
        }
    }
    #pragma unroll
    for (int u = 0; u < 2; ++u)
        #pragma unroll
        for (int v = 0; v < 2; ++v) {
            int c = rowbase + ty * 2 + u, e = colbase + tx * 2 + v;
            float a = acc[u][v];
            unsigned short hu = f2bf_u(a);
            size_t fidx = (((size_t)(e >> 4) * 56 + i * 8 + (c >> 5)) * 64
                           + (e & 15) + (((c >> 3) & 3) << 4)) * 8 + (c & 7);
            DThi[fidx] = hu;
            DTlo[fidx] = f2bf_u(a - bfu2f(hu));
        }
}

// ---------------------------------------------------------------------------
// Bias path (proven round-5). c0 aliases Mtmp (dead after wcomb2).
// ---------------------------------------------------------------------------
__global__ __launch_bounds__(256) void bias1_kernel(
    const void* sl, const void* sa, const void* sv, const void* outb,
    const void* slb, const void* sab, const void* svb,
    const int* __restrict__ flag, float* __restrict__ c0)
{
    int f32 = *flag;
    int r2 = blockIdx.x, m = threadIdx.x;
    __shared__ float red[256];
    float acc = 0.f;
    #pragma unroll
    for (int i = 0; i < 7; ++i)
        acc += ldu(outb, i * 256 + m, f32) * gsum_load(i, r2, m, sl, sa, sv, f32);
    red[m] = acc;
    __syncthreads();
    for (int s = 128; s > 0; s >>= 1) {
        if (m < s) red[m] += red[m + s];
        __syncthreads();
    }
    if (m == 0)
        c0[r2] = red[0] + ldu(slb, r2, f32) + ldu(sab, r2, f32) + ldu(svb, r2, f32);
}

__global__ __launch_bounds__(256) void bias2_kernel(
    const float* __restrict__ c0, const void* finalw, const void* finalb,
    const int* __restrict__ flag, float* __restrict__ d0)
{
    int f32 = *flag;
    int e = blockIdx.x, r = threadIdx.x;
    __shared__ float red[256];
    red[r] = c0[r] * ldu(finalw, (size_t)e * 256 + r, f32);
    __syncthreads();
    for (int s = 128; s > 0; s >>= 1) {
        if (r < s) red[r] += red[r + s];
        __syncthreads();
    }
    if (r == 0)
        d0[e] = red[0] + ldu(finalb, e, f32);
}

// ---------------------------------------------------------------------------
// Kernel 4 (proven round-13, MFMA + fragment-major): result = O@Dstack + d0.
// ---------------------------------------------------------------------------
__global__ __launch_bounds__(256) void final_gemm_mfma_kernel(
    const unsigned short* __restrict__ Ohi, const unsigned short* __restrict__ Olo,
    const unsigned short* __restrict__ DThi, const unsigned short* __restrict__ DTlo,
    const float* __restrict__ d0, const int* __restrict__ flag,
    void* __restrict__ outv)
{
    int f32 = *flag;
    int bx = blockIdx.x;
    int by = blockIdx.y;
    int w  = threadIdx.x >> 6;
    int lane = threadIdx.x & 63;
    int m = lane & 15, quad = lane >> 4;
    int R0 = by * 16, C0 = bx * 64 + w * 16;

    int t0 = R0 >> 2, t1 = (R0 + 15) >> 2;
    int g0 = (t0 < 300) ? 0 : (t0 < 550 ? 1 : 2);
    int g1 = (t1 < 300) ? 0 : (t1 < 550 ? 1 : 2);
    int activeset = (1 << g0) | (1 << g1);
    const int masks[7] = {7, 3, 5, 6, 1, 2, 4};

    const unsigned short* Abase_h = Ohi + (size_t)by * 56 * 512 + lane * 8;
    const unsigned short* Abase_l = Olo + (size_t)by * 56 * 512 + lane * 8;
    const unsigned short* Bbase_h = DThi + (size_t)(bx * 4 + w) * 56 * 512 + lane * 8;
    const unsigned short* Bbase_l = DTlo + (size_t)(bx * 4 + w) * 56 * 512 + lane * 8;

    f32x4 acc = {};
    for (int i = 0; i < 7; ++i) {
        if (!(masks[i] & activeset)) continue;
        #pragma unroll
        for (int kb = 0; kb < 8; ++kb) {
            size_t off = (size_t)(i * 8 + kb) * 512;
            bf16x8 ah = *(const bf16x8*)(Abase_h + off);
            bf16x8 al = *(const bf16x8*)(Abase_l + off);
            bf16x8 bh = *(const bf16x8*)(Bbase_h + off);
            bf16x8 bl = *(const bf16x8*)(Bbase_l + off);
            acc = __builtin_amdgcn_mfma_f32_16x16x32_bf16(ah, bh, acc, 0, 0, 0);
            acc = __builtin_amdgcn_mfma_f32_16x16x32_bf16(ah, bl, acc, 0, 0, 0);
            acc = __builtin_amdgcn_mfma_f32_16x16x32_bf16(al, bh, acc, 0, 0, 0);
        }
    }
    float dv = d0[C0 + m];
    #pragma unroll
    for (int r = 0; r < 4; ++r) {
        int row = R0 + quad * 4 + r;
        int col = C0 + m;
        float val = acc[r] + dv;
        if (f32) ((float*)outv)[(size_t)row * 256 + col] = val;
        else ((__hip_bfloat16*)outv)[(size_t)row * 256 + col] = __float2bfloat16(val);
    }
}

// ---------------------------------------------------------------------------
extern "C" void kernel_launch(void* const* d_in, const int* in_sizes, int n_in,
                              void* d_out, int out_size, void* d_ws, size_t ws_size,
                              hipStream_t stream) {
    const void* query     = d_in[0];
    const void* key       = d_in[1];
    const void* value     = d_in[2];
    const void* in_proj_w = d_in[3];
    const void* in_proj_b = d_in[4];
    const void* out_w     = d_in[5];
    const void* out_b     = d_in[6];
    const void* s_l_w     = d_in[7];
    const void* s_l_b     = d_in[8];
    const void* s_a_w     = d_in[9];
    const void* s_a_b     = d_in[10];
    const void* s_v_w     = d_in[11];
    const void* s_v_b     = d_in[12];
    const void* final_w   = d_in[13];
    const void* final_b   = d_in[14];

    float* ws     = (float*)d_ws;
    float* qws    = ws;                 //   786432 f (q fp32)
    unsigned short* KGh = (unsigned short*)(ws + 786432);
    unsigned short* KGl = KGh + 786432;
    unsigned short* VGh = (unsigned short*)(ws + 1572864);
    unsigned short* VGl = VGh + 786432;
    // O region [2359296, 7864320): Ohi/Olo for attn+final; aliased by the
    // conversion buffers XF/WF/GF/OWF (all consumed before attn writes O).
    unsigned short* Ohi = (unsigned short*)(ws + 2359296);   // 5505024 bf16
    unsigned short* Olo = (unsigned short*)(ws + 5111808);   // 5505024 bf16
    unsigned short* XFh = (unsigned short*)(ws + 2359296);   // 2359296 bf16
    unsigned short* XFl = XFh + 2359296;                     // 2359296 bf16
    unsigned short* WFh = XFl + 2359296;                     //  196608 bf16
    unsigned short* WFl = WFh + 196608;                      //  196608 bf16
    unsigned short* GFh = (unsigned short*)(ws + 4915200);   //  458752 bf16
    unsigned short* GFl = GFh + 458752;
    unsigned short* OWFh = GFl + 458752;                     //  458752 bf16
    unsigned short* OWFl = OWFh + 458752;                    // ends f 5832704
    float* Mtmp   = ws + 7864320;       //   458752 f
    unsigned short* DThi = (unsigned short*)(ws + 8323072);  // 458752 bf16
    unsigned short* DTlo = (unsigned short*)(ws + 8552448);  // 458752 bf16
    float* d0     = ws + 8781824;       //      256 f
    int*   flag   = (int*)(ws + 8782080);  // 1 int — proven footprint HIGH-WATER
    float* c0     = Mtmp;               // ALIAS: Mtmp dead after wcomb2

    detect_kernel<<<1, 64, 0, stream>>>((const unsigned short*)query, flag);
    conv_kernel<<<1696, 256, 0, stream>>>(query, key, value, in_proj_w,
                                          s_l_w, s_a_w, s_v_w, out_w, flag,
                                          XFh, XFl, WFh, WFl,
                                          GFh, GFl, OWFh, OWFl);
    qkv_mfma_kernel<<<dim3(12, 192), 256, 0, stream>>>(XFh, XFl, WFh, WFl,
                                                       in_proj_b, flag, qws,
                                                       KGh, KGl, VGh, VGl);
    wcomb1_mfma_kernel<<<dim3(4, 16, 7), 256, 0, stream>>>(GFh, GFl, OWFh, OWFl,
                                                           Mtmp);
    attn_mfma_kernel<<<dim3(24, 32), 256, 0, stream>>>(qws, KGh, KGl, VGh, VGl,
                                                       Ohi, Olo);
    wcomb2_gemm_kernel<<<dim3(8, 8, 7), 256, 0, stream>>>(Mtmp, final_w, flag,
                                                          DThi, DTlo);
    bias1_kernel<<<256, 256, 0, stream>>>(s_l_w, s_a_w, s_v_w, out_b,
                                          s_l_b, s_a_b, s_v_b, flag, c0);
    bias2_kernel<<<256, 256, 0, stream>>>(c0, final_w, final_b, flag, d0);
    final_gemm_mfma_kernel<<<dim3(4, 192), 256, 0, stream>>>(Ohi, Olo, DThi, DTlo,
                                                             d0, flag, d_out);
}